// Round 4
// baseline (449.095 us; speedup 1.0000x reference)
//
#include <hip/hip_runtime.h>
#include <math.h>

#define NB   32
#define C_   8
#define D_   4
#define H_   256
#define W_   256
#define HP   128
#define WP   128
#define MC   16
#define HO   126
#define WO   126
#define PATCH 144
#define OUTD 128
#define NL   (HO*WO)
#define HOG  6            // output rows per gemm block (126 = 6*21)
#define NGRP (HO/HOG)     // 21
#define BROW 160          // B row stride (bf16): 320 B -> conflict-free for b128 frags

typedef float  f32x4  __attribute__((ext_vector_type(4)));
typedef __bf16 bf16x8 __attribute__((ext_vector_type(8)));

// ---------------- Kernel 1: LPPool3d (2,2,2, p=2) -> merged[n][hp][wp][mc] bf16 ------
// mc = dp*8 + c contiguous innermost: this IS the GEMM's A/P layout (K = tap*16+mc).
// No LDS, low VGPR -> 8 waves/SIMD to hide HBM latency. 285 MB total traffic.
__global__ __launch_bounds__(256, 8) void pool_kernel(const float* __restrict__ x,
                                                      __bf16* __restrict__ merged) {
    int t  = threadIdx.x;
    int wp = t & 127;
    int hp = (blockIdx.x & 63) * 2 + (t >> 7);
    int n  = blockIdx.x >> 6;

    const float* xb = x + (size_t)n * (C_*D_*H_*W_) + 2*hp*W_ + 2*wp;
    bf16x8 lo, hi;
#pragma unroll
    for (int mc = 0; mc < 16; mc++) {
        int dp = mc >> 3, c = mc & 7;
        const float* p = xb + (size_t)(c*4 + 2*dp) * (H_*W_);
        float2 a0 = *(const float2*)(p);
        float2 a1 = *(const float2*)(p + W_);
        float2 a2 = *(const float2*)(p + H_*W_);
        float2 a3 = *(const float2*)(p + H_*W_ + W_);
        float s = a0.x*a0.x + a0.y*a0.y + a1.x*a1.x + a1.y*a1.y
                + a2.x*a2.x + a2.y*a2.y + a3.x*a3.x + a3.y*a3.y;
        if (mc < 8) lo[mc] = (__bf16)sqrtf(s); else hi[mc-8] = (__bf16)sqrtf(s);
    }
    __bf16* dst = merged + (((size_t)n*HP + hp)*WP + wp) * MC;
    *(bf16x8*)dst       = lo;
    *(bf16x8*)(dst + 8) = hi;
}

// ---------------- Kernel 2: im2col-free MFMA GEMM + bias + CELU + patch-reduce -------
__global__ __launch_bounds__(256, 2)
void gemm_kernel(const __bf16* __restrict__ merged, const float* __restrict__ lin_w,
                 const float* __restrict__ lin_b, float* __restrict__ accg) {
    __shared__ __align__(16) char smem[9*128*32 + OUTD*BROW*2];   // 36864 + 40960 B
    __bf16* Pl   = (__bf16*)smem;                  // P[row][wp][mc], row 8 = zeros
    __bf16* Blds = (__bf16*)(smem + 9*128*32);     // B[o][k_new], k_new = tap*16+mc

    int blk = blockIdx.x;
    int g = blk % NGRP, n = blk / NGRP;
    int ho0 = g * HOG;
    int t = threadIdx.x;
    int wave = t >> 6, lane = t & 63, quad = lane >> 4, l16 = lane & 15;

    // ---- P staging: straight vectorized copy of 8 rows (4 KB each) + zero row ----
    {
        const __bf16* msrc = merged + ((size_t)n*HP + ho0) * WP * MC;
#pragma unroll
        for (int i = 0; i < 8; i++)
            *(bf16x8*)&Pl[i*2048 + t*8] = *(const bf16x8*)&msrc[i*2048 + t*8];
        bf16x8 z = {};
        *(bf16x8*)&Pl[8*2048 + t*8] = z;
    }

    // ---- B staging, reordered: Blds[o][tap*16+mc] = W[o][mc*9+tap]; tap 9 = 0 ----
    {
        int o = t & 127, kh = t >> 7;
#pragma unroll 4
        for (int kk = 0; kk < BROW/2; kk++) {
            int kn = kh*(BROW/2) + kk;
            int tap = kn >> 4, mc = kn & 15;
            float v = (tap < 9) ? lin_w[o*PATCH + mc*9 + tap] : 0.f;
            Blds[o*BROW + kn] = (__bf16)v;
        }
    }

    float lb[8];
#pragma unroll
    for (int nt = 0; nt < 8; nt++) lb[nt] = lin_b[nt*16 + l16];

    float msk[2][4];
#pragma unroll
    for (int mt = 0; mt < 2; mt++)
#pragma unroll
        for (int r = 0; r < 4; r++)
            msk[mt][r] = (wave*32 + mt*16 + quad*4 + r < WO) ? 1.f : 0.f;

    __syncthreads();

    float srun[8] = {0,0,0,0,0,0,0,0};
    int h8 = (quad & 1) * 8;
    int m0 = wave * 32 + l16;

    for (int hh = 0; hh < HOG; hh++) {
        f32x4 acc[2][8] = {};
#pragma unroll
        for (int ks = 0; ks < 5; ks++) {
            int tap = 2*ks + (quad >> 1);
            int it = (tap * 11) >> 5;            // tap/3
            int jt = tap - it * 3;               // tap%3
            bf16x8 afr[2];
#pragma unroll
            for (int mt = 0; mt < 2; mt++) {
                int m = m0 + mt*16;
                afr[mt] = *(const bf16x8*)&Pl[((hh + it)*128 + m + jt)*16 + h8];
            }
#pragma unroll
            for (int nt = 0; nt < 8; nt++) {
                bf16x8 bfr = *(const bf16x8*)&Blds[(nt*16 + l16)*BROW + ks*32 + quad*8];
                acc[0][nt] = __builtin_amdgcn_mfma_f32_16x16x32_bf16(afr[0], bfr, acc[0][nt], 0, 0, 0);
                acc[1][nt] = __builtin_amdgcn_mfma_f32_16x16x32_bf16(afr[1], bfr, acc[1][nt], 0, 0, 0);
            }
        }
        // epilogue: bias + CELU + mask + reduce over patch rows
#pragma unroll
        for (int nt = 0; nt < 8; nt++) {
            float s = 0.f;
#pragma unroll
            for (int mt = 0; mt < 2; mt++) {
#pragma unroll
                for (int r = 0; r < 4; r++) {
                    float p = acc[mt][nt][r] + lb[nt];
                    float a = (p > 0.f) ? p : (__expf(p) - 1.f);
                    s += msk[mt][r] * a;
                }
            }
            s += __shfl_xor(s, 16, 64);
            s += __shfl_xor(s, 32, 64);
            srun[nt] += s;
        }
    }

    __syncthreads();                       // all P/B reads done; alias red over P
    float* red = (float*)smem;
    if (quad == 0) {
#pragma unroll
        for (int nt = 0; nt < 8; nt++) red[wave*OUTD + nt*16 + l16] = srun[nt];
    }
    __syncthreads();
    if (t < OUTD) {
        float tot = red[t] + red[OUTD+t] + red[2*OUTD+t] + red[3*OUTD+t];
        atomicAdd(&accg[n*OUTD + t], tot);
    }
}

// ---------------- Kernel 3: mean + clamped L2 normalize ------------------------------
__global__ void finalize_kernel(const float* __restrict__ acc, float* __restrict__ out) {
    int n = blockIdx.x;
    int o = threadIdx.x;     // 128 threads
    float a = acc[n * OUTD + o] * (1.0f / (float)NL);
    float s = a * a;
#pragma unroll
    for (int off = 32; off > 0; off >>= 1) s += __shfl_down(s, off, 64);
    __shared__ float partial[2];
    if ((o & 63) == 0) partial[o >> 6] = s;
    __syncthreads();
    float norm = sqrtf(partial[0] + partial[1]);
    norm = fmaxf(norm, 1e-6f);
    out[n * OUTD + o] = a / norm;
}

extern "C" void kernel_launch(void* const* d_in, const int* in_sizes, int n_in,
                              void* d_out, int out_size, void* d_ws, size_t ws_size,
                              hipStream_t stream) {
    const float* x     = (const float*)d_in[0];
    const float* lin_w = (const float*)d_in[1];
    const float* lin_b = (const float*)d_in[2];
    float* out = (float*)d_out;

    float*  acc    = (float*)d_ws;                       // 32*128 fp32 = 16 KB
    __bf16* merged = (__bf16*)((char*)d_ws + NB*OUTD*4); // 16.78 MB bf16

    hipMemsetAsync(acc, 0, NB * OUTD * sizeof(float), stream);

    pool_kernel<<<NB * 64, 256, 0, stream>>>(x, merged);
    gemm_kernel<<<NB * NGRP, 256, 0, stream>>>(merged, lin_w, lin_b, acc);
    finalize_kernel<<<NB, OUTD, 0, stream>>>(acc, out);
}